// Round 8
// baseline (501.631 us; speedup 1.0000x reference)
//
#include <hip/hip_runtime.h>

// y[b,h,l] = sum_{m<=l} x[b,h,m] k[h,l-m] + D[h] x[b,h,l]   (C = 1)
// One block per h, 256 threads. 8192-pt FFT as 5 radix passes (radix-8 x4 +
// radix-2 edges), 4 LDS exchanges; each thread does its 4 butterfly groups
// per pass SEQUENTIALLY so live state stays ~20 regs + kspec[32] (64 regs).
//
// Resource law (r1-r7 measured): 1024-thr blocks pin VGPR=64 -> ~1.1 GB HBM
// spill traffic, no attribute overrides it. 256-thr blocks get natural
// allocation (r1: 92 VGPR, WRITE == output exactly). So: 256 threads.
#define Bdim 4
#define Hdim 1024
#define Ldim 4096
#define NFFT 8192
#define NTHR 256
#define R2C 0.70710678118654752440f

// LDS float2-index swizzle: breaks power-of-2 stride conflicts.
__device__ __forceinline__ int SW(int i) { return i ^ ((i >> 4) & 15); }

// v_sin_f32 / v_cos_f32 take input in REVOLUTIONS (D = sin(S0*2pi)).
__device__ __forceinline__ void sincos_rev(float f, float& s, float& c) {
#if __has_builtin(__builtin_amdgcn_sinf) && __has_builtin(__builtin_amdgcn_cosf)
    s = __builtin_amdgcn_sinf(f);
    c = __builtin_amdgcn_cosf(f);
#else
    __sincosf(f * 6.28318530717958647692f, &s, &c);
#endif
}

__device__ __forceinline__ float2 cadd(float2 a, float2 b) { return make_float2(a.x + b.x, a.y + b.y); }
__device__ __forceinline__ float2 csub(float2 a, float2 b) { return make_float2(a.x - b.x, a.y - b.y); }
__device__ __forceinline__ float2 cmul(float2 a, float2 b) {
    return make_float2(a.x * b.x - a.y * b.y, a.x * b.y + a.y * b.x);
}
__device__ __forceinline__ float2 cmuli(float2 a)    { return make_float2(-a.y, a.x); }  // a * (+i)
__device__ __forceinline__ float2 cmulnegi(float2 a) { return make_float2(a.y, -a.x); }  // a * (-i)

// ---- forward radix-8 (DIF halves {4s,2s,s}), w = exp(-2pi i (g mod s)/(8s)) ----
__device__ __forceinline__ void fwd8_bc(float2 e[8], float2 w) {
    float2 w2  = cmul(w, w);
    float2 w2n = cmulnegi(w2);
    {   float2 u, d;
        u = e[0]; d = csub(u, e[2]); e[0] = cadd(u, e[2]); e[2] = cmul(d, w2);
        u = e[1]; d = csub(u, e[3]); e[1] = cadd(u, e[3]); e[3] = cmul(d, w2n);
        u = e[4]; d = csub(u, e[6]); e[4] = cadd(u, e[6]); e[6] = cmul(d, w2);
        u = e[5]; d = csub(u, e[7]); e[5] = cadd(u, e[7]); e[7] = cmul(d, w2n);
    }
    float2 w4 = cmul(w2, w2);
    {   float2 u, d;
        u = e[0]; d = csub(u, e[1]); e[0] = cadd(u, e[1]); e[1] = cmul(d, w4);
        u = e[2]; d = csub(u, e[3]); e[2] = cadd(u, e[3]); e[3] = cmul(d, w4);
        u = e[4]; d = csub(u, e[5]); e[4] = cadd(u, e[5]); e[5] = cmul(d, w4);
        u = e[6]; d = csub(u, e[7]); e[6] = cadd(u, e[7]); e[7] = cmul(d, w4);
    }
}
__device__ __forceinline__ void fwd8(float2 e[8], float2 w) {
    float2 w1  = make_float2(R2C * (w.x + w.y), R2C * (w.y - w.x)); // w*W8^1
    float2 w2t = cmulnegi(w);                                        // w*W8^2
    float2 w3  = cmulnegi(w1);                                       // w*W8^3
    {   float2 u, d;
        u = e[0]; d = csub(u, e[4]); e[0] = cadd(u, e[4]); e[4] = cmul(d, w);
        u = e[1]; d = csub(u, e[5]); e[1] = cadd(u, e[5]); e[5] = cmul(d, w1);
        u = e[2]; d = csub(u, e[6]); e[2] = cadd(u, e[6]); e[6] = cmul(d, w2t);
        u = e[3]; d = csub(u, e[7]); e[3] = cadd(u, e[7]); e[7] = cmul(d, w3);
    }
    fwd8_bc(e, w);
}
// First pass variant: inputs e[4..7] are zero (zero-padded upper half).
__device__ __forceinline__ void fwd8_zero(float2 e[8], float2 w) {
    float2 w1  = make_float2(R2C * (w.x + w.y), R2C * (w.y - w.x));
    float2 w2t = cmulnegi(w);
    float2 w3  = cmulnegi(w1);
    e[4] = cmul(e[0], w); e[5] = cmul(e[1], w1);
    e[6] = cmul(e[2], w2t); e[7] = cmul(e[3], w3);
    fwd8_bc(e, w);
}

// ---- inverse radix-8 (DIT halves {s,2s,4s}), v = exp(+2pi i (g mod s)/(8s)) ----
__device__ __forceinline__ void inv8(float2 e[8], float2 v) {
    float2 v2 = cmul(v, v);
    float2 v4 = cmul(v2, v2);
    {   float2 u, tv;
        u = e[0]; tv = cmul(e[1], v4); e[0] = cadd(u, tv); e[1] = csub(u, tv);
        u = e[2]; tv = cmul(e[3], v4); e[2] = cadd(u, tv); e[3] = csub(u, tv);
        u = e[4]; tv = cmul(e[5], v4); e[4] = cadd(u, tv); e[5] = csub(u, tv);
        u = e[6]; tv = cmul(e[7], v4); e[6] = cadd(u, tv); e[7] = csub(u, tv);
    }
    float2 v2i = cmuli(v2);
    {   float2 u, tv;
        u = e[0]; tv = cmul(e[2], v2);  e[0] = cadd(u, tv); e[2] = csub(u, tv);
        u = e[1]; tv = cmul(e[3], v2i); e[1] = cadd(u, tv); e[3] = csub(u, tv);
        u = e[4]; tv = cmul(e[6], v2);  e[4] = cadd(u, tv); e[6] = csub(u, tv);
        u = e[5]; tv = cmul(e[7], v2i); e[5] = cadd(u, tv); e[7] = csub(u, tv);
    }
    float2 q1 = make_float2(R2C * (v.x - v.y), R2C * (v.x + v.y)); // v*V8^1
    float2 q2 = cmuli(v);                                           // v*V8^2
    float2 q3 = cmuli(q1);                                          // v*V8^3
    {   float2 u, tv;
        u = e[0]; tv = cmul(e[4], v);  e[0] = cadd(u, tv); e[4] = csub(u, tv);
        u = e[1]; tv = cmul(e[5], q1); e[1] = cadd(u, tv); e[5] = csub(u, tv);
        u = e[2]; tv = cmul(e[6], q2); e[2] = cadd(u, tv); e[6] = csub(u, tv);
        u = e[3]; tv = cmul(e[7], q3); e[3] = cadd(u, tv); e[7] = csub(u, tv);
    }
}
// Specialized inv8 with v = 1 (s=1 pass: all twiddles constant).
__device__ __forceinline__ void inv8_unit(float2 e[8]) {
    {   float2 a, b;
        a = e[0]; b = e[1]; e[0] = cadd(a, b); e[1] = csub(a, b);
        a = e[2]; b = e[3]; e[2] = cadd(a, b); e[3] = csub(a, b);
        a = e[4]; b = e[5]; e[4] = cadd(a, b); e[5] = csub(a, b);
        a = e[6]; b = e[7]; e[6] = cadd(a, b); e[7] = csub(a, b);
    }
    {   float2 u, tv;
        u = e[0]; tv = e[2];        e[0] = cadd(u, tv); e[2] = csub(u, tv);
        u = e[1]; tv = cmuli(e[3]); e[1] = cadd(u, tv); e[3] = csub(u, tv);
        u = e[4]; tv = e[6];        e[4] = cadd(u, tv); e[6] = csub(u, tv);
        u = e[5]; tv = cmuli(e[7]); e[5] = cadd(u, tv); e[7] = csub(u, tv);
    }
    {   float2 u, tv;
        u = e[0]; tv = e[4];        e[0] = cadd(u, tv); e[4] = csub(u, tv);
        u = e[1]; tv = make_float2(R2C * (e[5].x - e[5].y), R2C * (e[5].x + e[5].y));
                                    e[1] = cadd(u, tv); e[5] = csub(u, tv);
        u = e[2]; tv = cmuli(e[6]); e[2] = cadd(u, tv); e[6] = csub(u, tv);
        u = e[3]; tv = make_float2(R2C * (-e[7].x - e[7].y), R2C * (e[7].x - e[7].y));
                                    e[3] = cadd(u, tv); e[7] = csub(u, tv);
    }
}

// LDS radix-8 passes, 4 groups/thread done sequentially. For S<=128 the
// twiddle is constant across groups (256 ≡ 0 mod S): one sincos per pass.
template<int S, int L>
__device__ __forceinline__ void pass_fwd(float2* A, int t) {
    float2 w;
    sincos_rev(-(float)(t & (S - 1)) * (1.0f / (8.0f * (float)S)), w.y, w.x);
    #pragma unroll
    for (int q = 0; q < 4; ++q) {
        const int g = t + NTHR * q;
        const int base = ((g >> L) << (L + 3)) | (g & (S - 1));
        float2 e[8];
        #pragma unroll
        for (int j = 0; j < 8; ++j) e[j] = A[SW(base + j * S)];
        fwd8(e, w);
        #pragma unroll
        for (int j = 0; j < 8; ++j) A[SW(base + j * S)] = e[j];
    }
}

template<int S, int L>
__device__ __forceinline__ void pass_inv(float2* A, int t) {
    float2 v;
    sincos_rev((float)(t & (S - 1)) * (1.0f / (8.0f * (float)S)), v.y, v.x);
    #pragma unroll
    for (int q = 0; q < 4; ++q) {
        const int g = t + NTHR * q;
        const int base = ((g >> L) << (L + 3)) | (g & (S - 1));
        float2 e[8];
        #pragma unroll
        for (int j = 0; j < 8; ++j) e[j] = A[SW(base + j * S)];
        inv8(e, v);
        #pragma unroll
        for (int j = 0; j < 8; ++j) A[SW(base + j * S)] = e[j];
    }
}

// inv pass S=512: g mod 512 alternates {t, t+256} -> two twiddle values.
__device__ __forceinline__ void pass_inv512(float2* A, int t) {
    float2 v0;
    sincos_rev((float)t * (1.0f / 4096.0f), v0.y, v0.x);
    const float2 stp = make_float2(0.92387953251f, 0.38268343236f); // exp(+2pi i/16)
    const float2 v1 = cmul(v0, stp);
    #pragma unroll
    for (int q = 0; q < 4; ++q) {
        const int g = t + NTHR * q;
        const int base = ((g >> 9) << 12) | (g & 511);
        const float2 v = (q & 1) ? v1 : v0;
        float2 e[8];
        #pragma unroll
        for (int j = 0; j < 8; ++j) e[j] = A[SW(base + j * 512)];
        inv8(e, v);
        #pragma unroll
        for (int j = 0; j < 8; ++j) A[SW(base + j * 512)] = e[j];
    }
}

__global__ __launch_bounds__(NTHR)
void fftconv_kernel(const float* __restrict__ x,
                    const float* __restrict__ kin,
                    const float* __restrict__ Din,
                    float* __restrict__ out)
{
    __shared__ float2 A[NFFT];   // 64 KiB -> 2 blocks/CU

    const int t = threadIdx.x;
    const int h = blockIdx.x;

    const float* kp = kin + (size_t)h * (size_t)Ldim;   // C = 1
    const float  Dh = Din[h];
    const float  invN = 1.0f / (float)NFFT;
    // step for the S=1024 load pass twiddle: exp(-2pi i * 256/8192)
    const float2 stpF = make_float2(0.98078528040f, -0.19509032202f);

    // ================= K: forward FFT, spectrum -> kspec regs =================
    {
        float2 w;                                   // exp(-2pi i g/8192), g=t+256q
        sincos_rev(-(float)t * (1.0f / 8192.0f), w.y, w.x);
        #pragma unroll
        for (int q = 0; q < 4; ++q) {
            const int g = t + NTHR * q;
            float2 e[8];
            #pragma unroll
            for (int j = 0; j < 4; ++j) e[j] = make_float2(kp[g + 1024 * j], 0.0f);
            fwd8_zero(e, w);
            #pragma unroll
            for (int j = 0; j < 8; ++j) A[SW(g + 1024 * j)] = e[j];
            w = cmul(w, stpF);
        }
    }
    __syncthreads();
    pass_fwd<128, 7>(A, t);  __syncthreads();
    pass_fwd<16, 4>(A, t);   __syncthreads();
    pass_fwd<2, 1>(A, t);    __syncthreads();
    // fwd half=1 stage (twiddle-free) + 1/N during stash into registers.
    float2 kspec[32];
    {
        #pragma unroll
        for (int q = 0; q < 4; ++q) {
            const int g = t + NTHR * q;
            float2 c[8];
            #pragma unroll
            for (int j = 0; j < 8; ++j) c[j] = A[SW(8 * g + j)];
            #pragma unroll
            for (int m = 0; m < 4; ++m) {
                float2 a = c[2 * m], b = c[2 * m + 1];
                kspec[8 * q + 2 * m]     = make_float2((a.x + b.x) * invN, (a.y + b.y) * invN);
                kspec[8 * q + 2 * m + 1] = make_float2((a.x - b.x) * invN, (a.y - b.y) * invN);
            }
        }
    }
    __syncthreads();   // stash reads others' slots; z-store below overwrites A

    // ================= batch pairs =================
    for (int p = 0; p < 2; ++p) {
        const float* xp0 = x + ((size_t)(2 * p)     * Hdim + h) * (size_t)Ldim;
        const float* xp1 = x + ((size_t)(2 * p + 1) * Hdim + h) * (size_t)Ldim;

        {   // z = x_b0 + i x_b1: load + fused first DIF stage (upper half zero)
            float2 w;
            sincos_rev(-(float)t * (1.0f / 8192.0f), w.y, w.x);
            #pragma unroll
            for (int q = 0; q < 4; ++q) {
                const int g = t + NTHR * q;
                float2 e[8];
                #pragma unroll
                for (int j = 0; j < 4; ++j)
                    e[j] = make_float2(xp0[g + 1024 * j], xp1[g + 1024 * j]);
                fwd8_zero(e, w);
                #pragma unroll
                for (int j = 0; j < 8; ++j) A[SW(g + 1024 * j)] = e[j];
                w = cmul(w, stpF);
            }
        }
        __syncthreads();
        pass_fwd<128, 7>(A, t);  __syncthreads();
        pass_fwd<16, 4>(A, t);   __syncthreads();
        pass_fwd<2, 1>(A, t);    __syncthreads();
        {   // mid: fwd half=1 + pointwise*kspec + inv halves {1,2,4}, in regs
            #pragma unroll
            for (int q = 0; q < 4; ++q) {
                const int g = t + NTHR * q;
                float2 c[8];
                #pragma unroll
                for (int j = 0; j < 8; ++j) c[j] = A[SW(8 * g + j)];
                #pragma unroll
                for (int m = 0; m < 4; ++m) {
                    float2 a = c[2 * m], b = c[2 * m + 1];
                    c[2 * m] = cadd(a, b); c[2 * m + 1] = csub(a, b);
                }
                #pragma unroll
                for (int j = 0; j < 8; ++j) c[j] = cmul(c[j], kspec[8 * q + j]);
                inv8_unit(c);
                #pragma unroll
                for (int j = 0; j < 8; ++j) A[SW(8 * g + j)] = c[j];
            }
        }
        __syncthreads();
        pass_inv<8, 3>(A, t);    __syncthreads();
        pass_inv<64, 6>(A, t);   __syncthreads();
        pass_inv512(A, t);       __syncthreads();
        {   // epilogue: last DIT stage (half=4096), low half only, + D*x skip.
            // x re-read from global (L2-warm) instead of 32 live registers.
            float* op0 = out + ((size_t)(2 * p)     * Hdim + h) * (size_t)Ldim;
            float* op1 = out + ((size_t)(2 * p + 1) * Hdim + h) * (size_t)Ldim;
            float2 w;                               // exp(+2pi i u/8192), u=t+256r
            sincos_rev((float)t * (1.0f / 8192.0f), w.y, w.x);
            const float2 stpE = make_float2(0.98078528040f, 0.19509032202f);
            #pragma unroll
            for (int r = 0; r < 16; ++r) {
                const int u = t + NTHR * r;
                float2 lo = A[SW(u)];
                float2 hi = cmul(A[SW(u + 4096)], w);
                op0[u] = (lo.x + hi.x) + Dh * xp0[u];
                op1[u] = (lo.y + hi.y) + Dh * xp1[u];
                w = cmul(w, stpE);
            }
        }
        // Epilogue reads only this thread's slots {t+256m}; the next pair's
        // z-store writes exactly the same set -> no extra barrier needed.
    }
}

extern "C" void kernel_launch(void* const* d_in, const int* in_sizes, int n_in,
                              void* d_out, int out_size, void* d_ws, size_t ws_size,
                              hipStream_t stream)
{
    const float* x  = (const float*)d_in[0];
    const float* k  = (const float*)d_in[1];
    const float* D  = (const float*)d_in[2];
    float* out = (float*)d_out;

    dim3 grid(Hdim);          // one block per h
    dim3 block(NTHR);
    hipLaunchKernelGGL(fftconv_kernel, grid, block, 0, stream, x, k, D, out);
}

// Round 9
// 143.531 us; speedup vs baseline: 3.4949x; 3.4949x over previous
//
#include <hip/hip_runtime.h>

// y[b,h,l] = sum_{m<=l} x[b,h,m] k[h,l-m] + D[h] x[b,h,l]   (C = 1)
//
// Two-kernel split (r8 lesson: any persistent K-spectrum in registers spills;
// the only clean allocations are 256-thr blocks with transient-only state):
//   kernel 1: per h, 8192-pt FFT of k -> spectrum (m2-folded, 1/N-scaled,
//             bitrev stash layout) -> d_ws (64 MB).
//   kernel 2: per (h, batch-pair), z = x_b0 + i x_b1 FFT -> pointwise with
//             Kspec streamed from global (transient 16 regs) -> inverse FFT
//             -> epilogue (last stage fused, + D*x skip with x re-read).
// Fallback if ws_size < 64 MB: r7 mono kernel (measured correct, 271 us).
#define Bdim 4
#define Hdim 1024
#define Ldim 4096
#define NFFT 8192
#define NTHR 256
#define R2C 0.70710678118654752440f

// LDS float2-index swizzle: breaks power-of-2 stride conflicts.
__device__ __forceinline__ int SW(int i) { return i ^ ((i >> 4) & 15); }

// v_sin_f32 / v_cos_f32 take input in REVOLUTIONS (D = sin(S0*2pi)).
__device__ __forceinline__ void sincos_rev(float f, float& s, float& c) {
#if __has_builtin(__builtin_amdgcn_sinf) && __has_builtin(__builtin_amdgcn_cosf)
    s = __builtin_amdgcn_sinf(f);
    c = __builtin_amdgcn_cosf(f);
#else
    __sincosf(f * 6.28318530717958647692f, &s, &c);
#endif
}

__device__ __forceinline__ float2 cadd(float2 a, float2 b) { return make_float2(a.x + b.x, a.y + b.y); }
__device__ __forceinline__ float2 csub(float2 a, float2 b) { return make_float2(a.x - b.x, a.y - b.y); }
__device__ __forceinline__ float2 cmul(float2 a, float2 b) {
    return make_float2(a.x * b.x - a.y * b.y, a.x * b.y + a.y * b.x);
}
__device__ __forceinline__ float2 cmuli(float2 a)    { return make_float2(-a.y, a.x); }  // a * (+i)
__device__ __forceinline__ float2 cmulnegi(float2 a) { return make_float2(a.y, -a.x); }  // a * (-i)

// ---- forward radix-8 (DIF halves {4s,2s,s}), w = exp(-2pi i (g mod s)/(8s)) ----
__device__ __forceinline__ void fwd8_bc(float2 e[8], float2 w) {
    float2 w2  = cmul(w, w);
    float2 w2n = cmulnegi(w2);
    {   float2 u, d;
        u = e[0]; d = csub(u, e[2]); e[0] = cadd(u, e[2]); e[2] = cmul(d, w2);
        u = e[1]; d = csub(u, e[3]); e[1] = cadd(u, e[3]); e[3] = cmul(d, w2n);
        u = e[4]; d = csub(u, e[6]); e[4] = cadd(u, e[6]); e[6] = cmul(d, w2);
        u = e[5]; d = csub(u, e[7]); e[5] = cadd(u, e[7]); e[7] = cmul(d, w2n);
    }
    float2 w4 = cmul(w2, w2);
    {   float2 u, d;
        u = e[0]; d = csub(u, e[1]); e[0] = cadd(u, e[1]); e[1] = cmul(d, w4);
        u = e[2]; d = csub(u, e[3]); e[2] = cadd(u, e[3]); e[3] = cmul(d, w4);
        u = e[4]; d = csub(u, e[5]); e[4] = cadd(u, e[5]); e[5] = cmul(d, w4);
        u = e[6]; d = csub(u, e[7]); e[6] = cadd(u, e[7]); e[7] = cmul(d, w4);
    }
}
__device__ __forceinline__ void fwd8(float2 e[8], float2 w) {
    float2 w1  = make_float2(R2C * (w.x + w.y), R2C * (w.y - w.x)); // w*W8^1
    float2 w2t = cmulnegi(w);                                        // w*W8^2
    float2 w3  = cmulnegi(w1);                                       // w*W8^3
    {   float2 u, d;
        u = e[0]; d = csub(u, e[4]); e[0] = cadd(u, e[4]); e[4] = cmul(d, w);
        u = e[1]; d = csub(u, e[5]); e[1] = cadd(u, e[5]); e[5] = cmul(d, w1);
        u = e[2]; d = csub(u, e[6]); e[2] = cadd(u, e[6]); e[6] = cmul(d, w2t);
        u = e[3]; d = csub(u, e[7]); e[3] = cadd(u, e[7]); e[7] = cmul(d, w3);
    }
    fwd8_bc(e, w);
}
// First pass variant: inputs e[4..7] are zero (zero-padded upper half).
__device__ __forceinline__ void fwd8_zero(float2 e[8], float2 w) {
    float2 w1  = make_float2(R2C * (w.x + w.y), R2C * (w.y - w.x));
    float2 w2t = cmulnegi(w);
    float2 w3  = cmulnegi(w1);
    e[4] = cmul(e[0], w); e[5] = cmul(e[1], w1);
    e[6] = cmul(e[2], w2t); e[7] = cmul(e[3], w3);
    fwd8_bc(e, w);
}

// ---- inverse radix-8 (DIT halves {s,2s,4s}), v = exp(+2pi i (g mod s)/(8s)) ----
__device__ __forceinline__ void inv8(float2 e[8], float2 v) {
    float2 v2 = cmul(v, v);
    float2 v4 = cmul(v2, v2);
    {   float2 u, tv;
        u = e[0]; tv = cmul(e[1], v4); e[0] = cadd(u, tv); e[1] = csub(u, tv);
        u = e[2]; tv = cmul(e[3], v4); e[2] = cadd(u, tv); e[3] = csub(u, tv);
        u = e[4]; tv = cmul(e[5], v4); e[4] = cadd(u, tv); e[5] = csub(u, tv);
        u = e[6]; tv = cmul(e[7], v4); e[6] = cadd(u, tv); e[7] = csub(u, tv);
    }
    float2 v2i = cmuli(v2);
    {   float2 u, tv;
        u = e[0]; tv = cmul(e[2], v2);  e[0] = cadd(u, tv); e[2] = csub(u, tv);
        u = e[1]; tv = cmul(e[3], v2i); e[1] = cadd(u, tv); e[3] = csub(u, tv);
        u = e[4]; tv = cmul(e[6], v2);  e[4] = cadd(u, tv); e[6] = csub(u, tv);
        u = e[5]; tv = cmul(e[7], v2i); e[5] = cadd(u, tv); e[7] = csub(u, tv);
    }
    float2 q1 = make_float2(R2C * (v.x - v.y), R2C * (v.x + v.y)); // v*V8^1
    float2 q2 = cmuli(v);                                           // v*V8^2
    float2 q3 = cmuli(q1);                                          // v*V8^3
    {   float2 u, tv;
        u = e[0]; tv = cmul(e[4], v);  e[0] = cadd(u, tv); e[4] = csub(u, tv);
        u = e[1]; tv = cmul(e[5], q1); e[1] = cadd(u, tv); e[5] = csub(u, tv);
        u = e[2]; tv = cmul(e[6], q2); e[2] = cadd(u, tv); e[6] = csub(u, tv);
        u = e[3]; tv = cmul(e[7], q3); e[3] = cadd(u, tv); e[7] = csub(u, tv);
    }
}
// Specialized inv8 with v = 1 (s=1 pass: all twiddles constant).
__device__ __forceinline__ void inv8_unit(float2 e[8]) {
    {   float2 a, b;
        a = e[0]; b = e[1]; e[0] = cadd(a, b); e[1] = csub(a, b);
        a = e[2]; b = e[3]; e[2] = cadd(a, b); e[3] = csub(a, b);
        a = e[4]; b = e[5]; e[4] = cadd(a, b); e[5] = csub(a, b);
        a = e[6]; b = e[7]; e[6] = cadd(a, b); e[7] = csub(a, b);
    }
    {   float2 u, tv;
        u = e[0]; tv = e[2];        e[0] = cadd(u, tv); e[2] = csub(u, tv);
        u = e[1]; tv = cmuli(e[3]); e[1] = cadd(u, tv); e[3] = csub(u, tv);
        u = e[4]; tv = e[6];        e[4] = cadd(u, tv); e[6] = csub(u, tv);
        u = e[5]; tv = cmuli(e[7]); e[5] = cadd(u, tv); e[7] = csub(u, tv);
    }
    {   float2 u, tv;
        u = e[0]; tv = e[4];        e[0] = cadd(u, tv); e[4] = csub(u, tv);
        u = e[1]; tv = make_float2(R2C * (e[5].x - e[5].y), R2C * (e[5].x + e[5].y));
                                    e[1] = cadd(u, tv); e[5] = csub(u, tv);
        u = e[2]; tv = cmuli(e[6]); e[2] = cadd(u, tv); e[6] = csub(u, tv);
        u = e[3]; tv = make_float2(R2C * (-e[7].x - e[7].y), R2C * (e[7].x - e[7].y));
                                    e[3] = cadd(u, tv); e[7] = csub(u, tv);
    }
}

// ===== 256-thread passes: 4 groups/thread, SEQUENTIAL (unroll 1) so only =====
// ===== one group's ~30 regs are live at a time (anti-spill, r8 lesson).  =====
template<int S, int L>
__device__ __forceinline__ void pass_fwd4(float2* A, int t) {
    float2 w;   // constant across q for S<=128 (256 ≡ 0 mod S)
    sincos_rev(-(float)(t & (S - 1)) * (1.0f / (8.0f * (float)S)), w.y, w.x);
    #pragma unroll 1
    for (int q = 0; q < 4; ++q) {
        const int g = t + NTHR * q;
        const int base = ((g >> L) << (L + 3)) | (g & (S - 1));
        float2 e[8];
        #pragma unroll
        for (int j = 0; j < 8; ++j) e[j] = A[SW(base + j * S)];
        fwd8(e, w);
        #pragma unroll
        for (int j = 0; j < 8; ++j) A[SW(base + j * S)] = e[j];
    }
}

template<int S, int L>
__device__ __forceinline__ void pass_inv4(float2* A, int t) {
    float2 v;
    sincos_rev((float)(t & (S - 1)) * (1.0f / (8.0f * (float)S)), v.y, v.x);
    #pragma unroll 1
    for (int q = 0; q < 4; ++q) {
        const int g = t + NTHR * q;
        const int base = ((g >> L) << (L + 3)) | (g & (S - 1));
        float2 e[8];
        #pragma unroll
        for (int j = 0; j < 8; ++j) e[j] = A[SW(base + j * S)];
        inv8(e, v);
        #pragma unroll
        for (int j = 0; j < 8; ++j) A[SW(base + j * S)] = e[j];
    }
}

// inv pass S=512: g mod 512 alternates {t, t+256} -> two twiddle values.
__device__ __forceinline__ void pass_inv512_4(float2* A, int t) {
    float2 v0;
    sincos_rev((float)t * (1.0f / 4096.0f), v0.y, v0.x);
    const float2 stp = make_float2(0.92387953251f, 0.38268343236f); // exp(+2pi i/16)
    const float2 v1 = cmul(v0, stp);
    #pragma unroll 1
    for (int q = 0; q < 4; ++q) {
        const int g = t + NTHR * q;
        const int base = ((g >> 9) << 12) | (g & 511);
        const float2 v = (q & 1) ? v1 : v0;
        float2 e[8];
        #pragma unroll
        for (int j = 0; j < 8; ++j) e[j] = A[SW(base + j * 512)];
        inv8(e, v);
        #pragma unroll
        for (int j = 0; j < 8; ++j) A[SW(base + j * 512)] = e[j];
    }
}

// ======================= kernel 1: K spectrum -> d_ws =======================
__global__ __launch_bounds__(NTHR)
void kspec_kernel(const float* __restrict__ kin, float2* __restrict__ kw)
{
    __shared__ float2 A[NFFT];   // 64 KiB
    const int t = threadIdx.x;
    const int h = blockIdx.x;
    const float* kp = kin + (size_t)h * (size_t)Ldim;
    const float invN = 1.0f / (float)NFFT;
    const float2 stpF = make_float2(0.98078528040f, -0.19509032202f); // exp(-2pi i/32)

    {   // load + fused first radix-8 pass (S=1024, upper half zero)
        float2 w;
        sincos_rev(-(float)t * (1.0f / 8192.0f), w.y, w.x);
        #pragma unroll 1
        for (int q = 0; q < 4; ++q) {
            const int g = t + NTHR * q;
            float2 e[8];
            #pragma unroll
            for (int j = 0; j < 4; ++j) e[j] = make_float2(kp[g + 1024 * j], 0.0f);
            fwd8_zero(e, w);
            #pragma unroll
            for (int j = 0; j < 8; ++j) A[SW(g + 1024 * j)] = e[j];
            w = cmul(w, stpF);
        }
    }
    __syncthreads();
    pass_fwd4<128, 7>(A, t);  __syncthreads();
    pass_fwd4<16, 4>(A, t);   __syncthreads();
    pass_fwd4<2, 1>(A, t);    __syncthreads();
    // fwd half=1 fold + 1/N, stored in stash layout idx = 8g+j (coalesced f4).
    float4* kw4 = reinterpret_cast<float4*>(kw + (size_t)h * NFFT);
    #pragma unroll 1
    for (int q = 0; q < 4; ++q) {
        const int g = t + NTHR * q;
        float2 c[8];
        #pragma unroll
        for (int j = 0; j < 8; ++j) c[j] = A[SW(8 * g + j)];
        #pragma unroll
        for (int m = 0; m < 4; ++m) {
            float2 a = c[2 * m], b = c[2 * m + 1];
            kw4[4 * g + m] = make_float4((a.x + b.x) * invN, (a.y + b.y) * invN,
                                         (a.x - b.x) * invN, (a.y - b.y) * invN);
        }
    }
}

// ================= kernel 2: per (h, pair) conv =================
__global__ __launch_bounds__(NTHR)
void conv_kernel(const float* __restrict__ x, const float2* __restrict__ kw,
                 const float* __restrict__ Din, float* __restrict__ out)
{
    __shared__ float2 A[NFFT];   // 64 KiB -> 2 blocks/CU
    const int t = threadIdx.x;
    const int h = blockIdx.x >> 1;       // adjacent blocks share h (L2/L3 reuse)
    const int p = blockIdx.x & 1;
    const float Dh = Din[h];
    const float* xp0 = x + ((size_t)(2 * p)     * Hdim + h) * (size_t)Ldim;
    const float* xp1 = x + ((size_t)(2 * p + 1) * Hdim + h) * (size_t)Ldim;
    const float2 stpF = make_float2(0.98078528040f, -0.19509032202f);

    {   // z = x_b0 + i x_b1: load + fused first radix-8 pass (upper half zero)
        float2 w;
        sincos_rev(-(float)t * (1.0f / 8192.0f), w.y, w.x);
        #pragma unroll 1
        for (int q = 0; q < 4; ++q) {
            const int g = t + NTHR * q;
            float2 e[8];
            #pragma unroll
            for (int j = 0; j < 4; ++j)
                e[j] = make_float2(xp0[g + 1024 * j], xp1[g + 1024 * j]);
            fwd8_zero(e, w);
            #pragma unroll
            for (int j = 0; j < 8; ++j) A[SW(g + 1024 * j)] = e[j];
            w = cmul(w, stpF);
        }
    }
    __syncthreads();
    pass_fwd4<128, 7>(A, t);  __syncthreads();
    pass_fwd4<16, 4>(A, t);   __syncthreads();
    pass_fwd4<2, 1>(A, t);    __syncthreads();
    {   // mid: fwd half=1 + pointwise*Kspec (streamed, transient) + inv {1,2,4}
        const float4* kw4 = reinterpret_cast<const float4*>(kw + (size_t)h * NFFT);
        #pragma unroll 1
        for (int q = 0; q < 4; ++q) {
            const int g = t + NTHR * q;
            float2 c[8];
            #pragma unroll
            for (int j = 0; j < 8; ++j) c[j] = A[SW(8 * g + j)];
            #pragma unroll
            for (int m = 0; m < 4; ++m) {
                float2 a = c[2 * m], b = c[2 * m + 1];
                c[2 * m] = cadd(a, b); c[2 * m + 1] = csub(a, b);
            }
            #pragma unroll
            for (int m = 0; m < 4; ++m) {
                float4 kv = kw4[4 * g + m];
                c[2 * m]     = cmul(c[2 * m],     make_float2(kv.x, kv.y));
                c[2 * m + 1] = cmul(c[2 * m + 1], make_float2(kv.z, kv.w));
            }
            inv8_unit(c);
            #pragma unroll
            for (int j = 0; j < 8; ++j) A[SW(8 * g + j)] = c[j];
        }
    }
    __syncthreads();
    pass_inv4<8, 3>(A, t);    __syncthreads();
    pass_inv4<64, 6>(A, t);   __syncthreads();
    pass_inv512_4(A, t);      __syncthreads();
    {   // epilogue: last DIT stage (half=4096), low half only, + D*x skip
        float* op0 = out + ((size_t)(2 * p)     * Hdim + h) * (size_t)Ldim;
        float* op1 = out + ((size_t)(2 * p + 1) * Hdim + h) * (size_t)Ldim;
        float2 w;                               // exp(+2pi i u/8192), u=t+256r
        sincos_rev((float)t * (1.0f / 8192.0f), w.y, w.x);
        const float2 stpE = make_float2(0.98078528040f, 0.19509032202f);
        #pragma unroll 1
        for (int r = 0; r < 16; ++r) {
            const int u = t + NTHR * r;
            float2 lo = A[SW(u)];
            float2 hi = cmul(A[SW(u + 4096)], w);
            op0[u] = (lo.x + hi.x) + Dh * xp0[u];
            op1[u] = (lo.y + hi.y) + Dh * xp1[u];
            w = cmul(w, stpE);
        }
    }
}

// ======================= fallback: r7 mono kernel (271 us) =======================
template<int S>
__device__ __forceinline__ void pass_fwd1(float2* A, int t) {
    constexpr int L = (S == 1024) ? 10 : (S == 128) ? 7 : (S == 16) ? 4 : 1;
    float2 w;
    sincos_rev(-(float)(t & (S - 1)) * (1.0f / (8.0f * (float)S)), w.y, w.x);
    const int base = ((t >> L) << (L + 3)) | (t & (S - 1));
    float2 e[8];
    #pragma unroll
    for (int j = 0; j < 8; ++j) e[j] = A[SW(base + j * S)];
    fwd8(e, w);
    #pragma unroll
    for (int j = 0; j < 8; ++j) A[SW(base + j * S)] = e[j];
}
template<int S>
__device__ __forceinline__ void pass_inv1(float2* A, int t) {
    constexpr int L = (S == 512) ? 9 : (S == 64) ? 6 : 3;
    float2 v;
    sincos_rev((float)(t & (S - 1)) * (1.0f / (8.0f * (float)S)), v.y, v.x);
    const int base = ((t >> L) << (L + 3)) | (t & (S - 1));
    float2 e[8];
    #pragma unroll
    for (int j = 0; j < 8; ++j) e[j] = A[SW(base + j * S)];
    inv8(e, v);
    #pragma unroll
    for (int j = 0; j < 8; ++j) A[SW(base + j * S)] = e[j];
}

__global__ void
__attribute__((amdgpu_flat_work_group_size(1024, 1024)))
fftconv_mono(const float* __restrict__ x,
             const float* __restrict__ kin,
             const float* __restrict__ Din,
             float* __restrict__ out)
{
    __shared__ float2 A[NFFT];
    __shared__ float2 Kb[NFFT];
    const int t = threadIdx.x;
    const int h = blockIdx.x;
    const float* kp = kin + (size_t)h * (size_t)Ldim;
    const float  Dh = Din[h];
    const float  invN = 1.0f / (float)NFFT;

    {
        float2 w;
        sincos_rev(-(float)t * (1.0f / 8192.0f), w.y, w.x);
        float2 e[8];
        #pragma unroll
        for (int j = 0; j < 4; ++j) e[j] = make_float2(kp[t + 1024 * j], 0.0f);
        fwd8_zero(e, w);
        #pragma unroll
        for (int j = 0; j < 8; ++j) A[SW(t + 1024 * j)] = e[j];
    }
    __syncthreads();
    pass_fwd1<128>(A, t);  __syncthreads();
    pass_fwd1<16>(A, t);   __syncthreads();
    pass_fwd1<2>(A, t);    __syncthreads();
    {
        float2 c[8];
        #pragma unroll
        for (int j = 0; j < 8; ++j) c[j] = A[SW(8 * t + j)];
        #pragma unroll
        for (int u2 = 0; u2 < 4; ++u2) {
            float2 a = c[2 * u2], b = c[2 * u2 + 1];
            Kb[SW(8 * t + 2 * u2)]     = make_float2((a.x + b.x) * invN, (a.y + b.y) * invN);
            Kb[SW(8 * t + 2 * u2 + 1)] = make_float2((a.x - b.x) * invN, (a.y - b.y) * invN);
        }
    }
    for (int p = 0; p < 2; ++p) {
        const float* xp0 = x + ((size_t)(2 * p)     * Hdim + h) * (size_t)Ldim;
        const float* xp1 = x + ((size_t)(2 * p + 1) * Hdim + h) * (size_t)Ldim;
        float xr0[4], xr1[4];
        __syncthreads();
        {
            float2 w;
            sincos_rev(-(float)t * (1.0f / 8192.0f), w.y, w.x);
            float2 e[8];
            #pragma unroll
            for (int j = 0; j < 4; ++j) {
                float a = xp0[t + 1024 * j], b = xp1[t + 1024 * j];
                xr0[j] = a; xr1[j] = b;
                e[j] = make_float2(a, b);
            }
            fwd8_zero(e, w);
            #pragma unroll
            for (int j = 0; j < 8; ++j) A[SW(t + 1024 * j)] = e[j];
        }
        __syncthreads();
        pass_fwd1<128>(A, t);  __syncthreads();
        pass_fwd1<16>(A, t);   __syncthreads();
        pass_fwd1<2>(A, t);    __syncthreads();
        {
            float2 c[8];
            #pragma unroll
            for (int j = 0; j < 8; ++j) c[j] = A[SW(8 * t + j)];
            #pragma unroll
            for (int u2 = 0; u2 < 4; ++u2) {
                float2 a = c[2 * u2], b = c[2 * u2 + 1];
                c[2 * u2] = cadd(a, b); c[2 * u2 + 1] = csub(a, b);
            }
            #pragma unroll
            for (int j = 0; j < 8; ++j) c[j] = cmul(c[j], Kb[SW(8 * t + j)]);
            inv8_unit(c);
            #pragma unroll
            for (int j = 0; j < 8; ++j) A[SW(8 * t + j)] = c[j];
        }
        __syncthreads();
        pass_inv1<8>(A, t);    __syncthreads();
        pass_inv1<64>(A, t);   __syncthreads();
        pass_inv1<512>(A, t);  __syncthreads();
        {
            float* op0 = out + ((size_t)(2 * p)     * Hdim + h) * (size_t)Ldim;
            float* op1 = out + ((size_t)(2 * p + 1) * Hdim + h) * (size_t)Ldim;
            float2 vf;
            sincos_rev((float)t * (1.0f / 8192.0f), vf.y, vf.x);
            float2 tws[4];
            tws[0] = vf;
            tws[1] = make_float2(R2C * (vf.x - vf.y), R2C * (vf.x + vf.y));
            tws[2] = cmuli(vf);
            tws[3] = cmuli(tws[1]);
            #pragma unroll
            for (int r = 0; r < 4; ++r) {
                int u = t + 1024 * r;
                float2 lo = A[SW(u)];
                float2 hi = cmul(A[SW(u + 4096)], tws[r]);
                op0[u] = (lo.x + hi.x) + Dh * xr0[r];
                op1[u] = (lo.y + hi.y) + Dh * xr1[r];
            }
        }
    }
}

extern "C" void kernel_launch(void* const* d_in, const int* in_sizes, int n_in,
                              void* d_out, int out_size, void* d_ws, size_t ws_size,
                              hipStream_t stream)
{
    const float* x  = (const float*)d_in[0];
    const float* k  = (const float*)d_in[1];
    const float* D  = (const float*)d_in[2];
    float* out = (float*)d_out;

    const size_t KW_BYTES = (size_t)Hdim * (size_t)NFFT * sizeof(float2); // 64 MB
    if (ws_size >= KW_BYTES) {
        float2* kw = (float2*)d_ws;
        hipLaunchKernelGGL(kspec_kernel, dim3(Hdim), dim3(NTHR), 0, stream, k, kw);
        hipLaunchKernelGGL(conv_kernel, dim3(2 * Hdim), dim3(NTHR), 0, stream,
                           x, kw, D, out);
    } else {
        hipLaunchKernelGGL(fftconv_mono, dim3(Hdim), dim3(1024), 0, stream,
                           x, k, D, out);
    }
}

// Round 11
// 112.638 us; speedup vs baseline: 4.4535x; 1.2743x over previous
//
#include <hip/hip_runtime.h>

// y[b,h,l] = sum_{m<=l} x[b,h,m] k[h,l-m] + D[h] x[b,h,l]   (C = 1)
//
// Half-size real-FFT scheme. Per row: z[n] = x[2n] + i x[2n+1] (n<2048, 0
// above), Z = FFT_4096(z) (12 standard radix-2 DIF stages fused as 4 radix-8
// passes -> bin k lands at array position bitrev12(k)). The rfft-unpack * Kf
// * irfft-pack midpoint collapses to
//   V[k]  = G1(k) Z[k]  + G2(k) conj(Z[4096-k])
//   V[kc] = G1c(k) Z[kc] + G2c(k) conj(Z[k])
// with G's precomputed per h by kspec_kernel -> d_ws (64 MB). Then
// v = IFFT_4096(V) (unnormalized; 1/M folded into G): y[2n] = Re v[n],
// y[2n+1] = Im v[n] (+ D*x skip). Specials: k=0 couples DC & Nyquist (real,
// positions 0 and 1 = bitrev12(2048)); k=2048 self-pair.
//
// r10 bug fixed: the permutation is FULL 12-bit reversal (passes are standard
// radix-2 DIF stages; verified twiddle-by-twiddle), NOT octal-digit reversal.
//
// Resource law (r1-r9): 256-thr blocks + transient-only state -> natural
// VGPR alloc, zero spill (r9: 88 VGPR, WRITE == output). Keep that shape.
#define Bdim 4
#define Hdim 1024
#define Ldim 4096
#define NH   4096
#define NTHR 256
#define R2C  0.70710678118654752440f
#define INVM (1.0f / 8192.0f)

__device__ __forceinline__ int SW(int i) { return i ^ ((i >> 4) & 15); }
__device__ __forceinline__ int bitrev12(int k) {
    return (int)(__brev((unsigned)k) >> 20);
}

__device__ __forceinline__ void sincos_rev(float f, float& s, float& c) {
#if __has_builtin(__builtin_amdgcn_sinf) && __has_builtin(__builtin_amdgcn_cosf)
    s = __builtin_amdgcn_sinf(f);
    c = __builtin_amdgcn_cosf(f);
#else
    __sincosf(f * 6.28318530717958647692f, &s, &c);
#endif
}

__device__ __forceinline__ float2 cadd(float2 a, float2 b) { return make_float2(a.x + b.x, a.y + b.y); }
__device__ __forceinline__ float2 csub(float2 a, float2 b) { return make_float2(a.x - b.x, a.y - b.y); }
__device__ __forceinline__ float2 cmul(float2 a, float2 b) {
    return make_float2(a.x * b.x - a.y * b.y, a.x * b.y + a.y * b.x);
}
__device__ __forceinline__ float2 cmuli(float2 a)    { return make_float2(-a.y, a.x); }
__device__ __forceinline__ float2 cmulnegi(float2 a) { return make_float2(a.y, -a.x); }
__device__ __forceinline__ float2 conjf(float2 a)    { return make_float2(a.x, -a.y); }

__device__ __forceinline__ void fwd8_bc(float2 e[8], float2 w) {
    float2 w2  = cmul(w, w);
    float2 w2n = cmulnegi(w2);
    {   float2 u, d;
        u = e[0]; d = csub(u, e[2]); e[0] = cadd(u, e[2]); e[2] = cmul(d, w2);
        u = e[1]; d = csub(u, e[3]); e[1] = cadd(u, e[3]); e[3] = cmul(d, w2n);
        u = e[4]; d = csub(u, e[6]); e[4] = cadd(u, e[6]); e[6] = cmul(d, w2);
        u = e[5]; d = csub(u, e[7]); e[5] = cadd(u, e[7]); e[7] = cmul(d, w2n);
    }
    float2 w4 = cmul(w2, w2);
    {   float2 u, d;
        u = e[0]; d = csub(u, e[1]); e[0] = cadd(u, e[1]); e[1] = cmul(d, w4);
        u = e[2]; d = csub(u, e[3]); e[2] = cadd(u, e[3]); e[3] = cmul(d, w4);
        u = e[4]; d = csub(u, e[5]); e[4] = cadd(u, e[5]); e[5] = cmul(d, w4);
        u = e[6]; d = csub(u, e[7]); e[6] = cadd(u, e[7]); e[7] = cmul(d, w4);
    }
}
__device__ __forceinline__ void fwd8_zero(float2 e[8], float2 w) {
    float2 w1  = make_float2(R2C * (w.x + w.y), R2C * (w.y - w.x));
    float2 w2t = cmulnegi(w);
    float2 w3  = cmulnegi(w1);
    e[4] = cmul(e[0], w); e[5] = cmul(e[1], w1);
    e[6] = cmul(e[2], w2t); e[7] = cmul(e[3], w3);
    fwd8_bc(e, w);
}
__device__ __forceinline__ void fwd8(float2 e[8], float2 w) {
    float2 w1  = make_float2(R2C * (w.x + w.y), R2C * (w.y - w.x));
    float2 w2t = cmulnegi(w);
    float2 w3  = cmulnegi(w1);
    {   float2 u, d;
        u = e[0]; d = csub(u, e[4]); e[0] = cadd(u, e[4]); e[4] = cmul(d, w);
        u = e[1]; d = csub(u, e[5]); e[1] = cadd(u, e[5]); e[5] = cmul(d, w1);
        u = e[2]; d = csub(u, e[6]); e[2] = cadd(u, e[6]); e[6] = cmul(d, w2t);
        u = e[3]; d = csub(u, e[7]); e[3] = cadd(u, e[7]); e[7] = cmul(d, w3);
    }
    fwd8_bc(e, w);
}
__device__ __forceinline__ void fwd8_unit(float2 e[8]) {
    {   float2 u, d;
        u = e[0]; d = csub(u, e[4]); e[0] = cadd(u, e[4]); e[4] = d;
        u = e[1]; d = csub(u, e[5]); e[1] = cadd(u, e[5]);
        e[5] = make_float2(R2C * (d.x + d.y), R2C * (d.y - d.x));
        u = e[2]; d = csub(u, e[6]); e[2] = cadd(u, e[6]); e[6] = cmulnegi(d);
        u = e[3]; d = csub(u, e[7]); e[3] = cadd(u, e[7]);
        e[7] = make_float2(R2C * (d.y - d.x), -R2C * (d.x + d.y));
    }
    {   float2 u, d;
        u = e[0]; d = csub(u, e[2]); e[0] = cadd(u, e[2]); e[2] = d;
        u = e[1]; d = csub(u, e[3]); e[1] = cadd(u, e[3]); e[3] = cmulnegi(d);
        u = e[4]; d = csub(u, e[6]); e[4] = cadd(u, e[6]); e[6] = d;
        u = e[5]; d = csub(u, e[7]); e[5] = cadd(u, e[7]); e[7] = cmulnegi(d);
    }
    {   float2 u;
        u = e[0]; e[0] = cadd(u, e[1]); e[1] = csub(u, e[1]);
        u = e[2]; e[2] = cadd(u, e[3]); e[3] = csub(u, e[3]);
        u = e[4]; e[4] = cadd(u, e[5]); e[5] = csub(u, e[5]);
        u = e[6]; e[6] = cadd(u, e[7]); e[7] = csub(u, e[7]);
    }
}

__device__ __forceinline__ void inv8(float2 e[8], float2 v) {
    float2 v2 = cmul(v, v);
    float2 v4 = cmul(v2, v2);
    {   float2 u, tv;
        u = e[0]; tv = cmul(e[1], v4); e[0] = cadd(u, tv); e[1] = csub(u, tv);
        u = e[2]; tv = cmul(e[3], v4); e[2] = cadd(u, tv); e[3] = csub(u, tv);
        u = e[4]; tv = cmul(e[5], v4); e[4] = cadd(u, tv); e[5] = csub(u, tv);
        u = e[6]; tv = cmul(e[7], v4); e[6] = cadd(u, tv); e[7] = csub(u, tv);
    }
    float2 v2i = cmuli(v2);
    {   float2 u, tv;
        u = e[0]; tv = cmul(e[2], v2);  e[0] = cadd(u, tv); e[2] = csub(u, tv);
        u = e[1]; tv = cmul(e[3], v2i); e[1] = cadd(u, tv); e[3] = csub(u, tv);
        u = e[4]; tv = cmul(e[6], v2);  e[4] = cadd(u, tv); e[6] = csub(u, tv);
        u = e[5]; tv = cmul(e[7], v2i); e[5] = cadd(u, tv); e[7] = csub(u, tv);
    }
    float2 q1 = make_float2(R2C * (v.x - v.y), R2C * (v.x + v.y));
    float2 q2 = cmuli(v);
    float2 q3 = cmuli(q1);
    {   float2 u, tv;
        u = e[0]; tv = cmul(e[4], v);  e[0] = cadd(u, tv); e[4] = csub(u, tv);
        u = e[1]; tv = cmul(e[5], q1); e[1] = cadd(u, tv); e[5] = csub(u, tv);
        u = e[2]; tv = cmul(e[6], q2); e[2] = cadd(u, tv); e[6] = csub(u, tv);
        u = e[3]; tv = cmul(e[7], q3); e[3] = cadd(u, tv); e[7] = csub(u, tv);
    }
}
__device__ __forceinline__ void inv8_unit(float2 e[8]) {
    {   float2 a, b;
        a = e[0]; b = e[1]; e[0] = cadd(a, b); e[1] = csub(a, b);
        a = e[2]; b = e[3]; e[2] = cadd(a, b); e[3] = csub(a, b);
        a = e[4]; b = e[5]; e[4] = cadd(a, b); e[5] = csub(a, b);
        a = e[6]; b = e[7]; e[6] = cadd(a, b); e[7] = csub(a, b);
    }
    {   float2 u, tv;
        u = e[0]; tv = e[2];        e[0] = cadd(u, tv); e[2] = csub(u, tv);
        u = e[1]; tv = cmuli(e[3]); e[1] = cadd(u, tv); e[3] = csub(u, tv);
        u = e[4]; tv = e[6];        e[4] = cadd(u, tv); e[6] = csub(u, tv);
        u = e[5]; tv = cmuli(e[7]); e[5] = cadd(u, tv); e[7] = csub(u, tv);
    }
    {   float2 u, tv;
        u = e[0]; tv = e[4];        e[0] = cadd(u, tv); e[4] = csub(u, tv);
        u = e[1]; tv = make_float2(R2C * (e[5].x - e[5].y), R2C * (e[5].x + e[5].y));
                                    e[1] = cadd(u, tv); e[5] = csub(u, tv);
        u = e[2]; tv = cmuli(e[6]); e[2] = cadd(u, tv); e[6] = csub(u, tv);
        u = e[3]; tv = make_float2(R2C * (-e[7].x - e[7].y), R2C * (e[7].x - e[7].y));
                                    e[3] = cadd(u, tv); e[7] = csub(u, tv);
    }
}
__device__ __forceinline__ void inv8_low(float2 e[8], float2 v) {
    float2 v2 = cmul(v, v);
    float2 v4 = cmul(v2, v2);
    {   float2 u, tv;
        u = e[0]; tv = cmul(e[1], v4); e[0] = cadd(u, tv); e[1] = csub(u, tv);
        u = e[2]; tv = cmul(e[3], v4); e[2] = cadd(u, tv); e[3] = csub(u, tv);
        u = e[4]; tv = cmul(e[5], v4); e[4] = cadd(u, tv); e[5] = csub(u, tv);
        u = e[6]; tv = cmul(e[7], v4); e[6] = cadd(u, tv); e[7] = csub(u, tv);
    }
    float2 v2i = cmuli(v2);
    {   float2 u, tv;
        u = e[0]; tv = cmul(e[2], v2);  e[0] = cadd(u, tv); e[2] = csub(u, tv);
        u = e[1]; tv = cmul(e[3], v2i); e[1] = cadd(u, tv); e[3] = csub(u, tv);
        u = e[4]; tv = cmul(e[6], v2);  e[4] = cadd(u, tv); e[6] = csub(u, tv);
        u = e[5]; tv = cmul(e[7], v2i); e[5] = cadd(u, tv); e[7] = csub(u, tv);
    }
    float2 q1 = make_float2(R2C * (v.x - v.y), R2C * (v.x + v.y));
    float2 q2 = cmuli(v);
    float2 q3 = cmuli(q1);
    e[0] = cadd(e[0], cmul(e[4], v));
    e[1] = cadd(e[1], cmul(e[5], q1));
    e[2] = cadd(e[2], cmul(e[6], q2));
    e[3] = cadd(e[3], cmul(e[7], q3));
}

template<int S, int L>
__device__ __forceinline__ void pass_fwd2(float2* A, int t) {
    float2 w;
    sincos_rev(-(float)(t & (S - 1)) * (1.0f / (8.0f * (float)S)), w.y, w.x);
    #pragma unroll 1
    for (int q = 0; q < 2; ++q) {
        const int g = t + NTHR * q;
        const int base = ((g >> L) << (L + 3)) | (g & (S - 1));
        float2 e[8];
        #pragma unroll
        for (int j = 0; j < 8; ++j) e[j] = A[SW(base + j * S)];
        fwd8(e, w);
        #pragma unroll
        for (int j = 0; j < 8; ++j) A[SW(base + j * S)] = e[j];
    }
}
template<int S, int L>
__device__ __forceinline__ void pass_inv2(float2* A, int t) {
    float2 v;
    sincos_rev((float)(t & (S - 1)) * (1.0f / (8.0f * (float)S)), v.y, v.x);
    #pragma unroll 1
    for (int q = 0; q < 2; ++q) {
        const int g = t + NTHR * q;
        const int base = ((g >> L) << (L + 3)) | (g & (S - 1));
        float2 e[8];
        #pragma unroll
        for (int j = 0; j < 8; ++j) e[j] = A[SW(base + j * S)];
        inv8(e, v);
        #pragma unroll
        for (int j = 0; j < 8; ++j) A[SW(base + j * S)] = e[j];
    }
}
__device__ __forceinline__ void pass_fwd_unit(float2* A, int t) {
    #pragma unroll 1
    for (int q = 0; q < 2; ++q) {
        const int base = (t + NTHR * q) << 3;
        float2 e[8];
        #pragma unroll
        for (int j = 0; j < 8; ++j) e[j] = A[SW(base + j)];
        fwd8_unit(e);
        #pragma unroll
        for (int j = 0; j < 8; ++j) A[SW(base + j)] = e[j];
    }
}
__device__ __forceinline__ void pass_inv_unit(float2* A, int t) {
    #pragma unroll 1
    for (int q = 0; q < 2; ++q) {
        const int base = (t + NTHR * q) << 3;
        float2 e[8];
        #pragma unroll
        for (int j = 0; j < 8; ++j) e[j] = A[SW(base + j)];
        inv8_unit(e);
        #pragma unroll
        for (int j = 0; j < 8; ++j) A[SW(base + j)] = e[j];
    }
}

__device__ __forceinline__ void load_fwd512(float2* A, int t, const float2* row2) {
    float2 w0;
    sincos_rev(-(float)t * (1.0f / 4096.0f), w0.y, w0.x);
    const float2 stp = make_float2(0.92387953251f, -0.38268343236f); // exp(-i pi/8)
    #pragma unroll 1
    for (int q = 0; q < 2; ++q) {
        const int g = t + NTHR * q;
        const float2 w = q ? cmul(w0, stp) : w0;
        float2 e[8];
        #pragma unroll
        for (int j = 0; j < 4; ++j) e[j] = row2[g + 512 * j];
        fwd8_zero(e, w);
        #pragma unroll
        for (int j = 0; j < 8; ++j) A[SW(g + 512 * j)] = e[j];
    }
}

__global__ __launch_bounds__(NTHR)
void kspec_kernel(const float* __restrict__ kin, float4* __restrict__ kw)
{
    __shared__ float2 A[NH];   // 32 KiB
    const int t = threadIdx.x;
    const int h = blockIdx.x;
    const float2* krow2 = reinterpret_cast<const float2*>(kin + (size_t)h * Ldim);

    load_fwd512(A, t, krow2);
    __syncthreads();
    pass_fwd2<64, 6>(A, t);  __syncthreads();
    pass_fwd2<8, 3>(A, t);   __syncthreads();
    pass_fwd_unit(A, t);     __syncthreads();

    float4* kw4 = kw + (size_t)h * NH;
    #pragma unroll 1
    for (int q = 0; q < 8; ++q) {
        const int k = t + NTHR * q;            // 0..2047
        if (k == 0) {
            float2 Z0 = A[SW(0)];     // Z[0]     (bitrev12(0)    = 0)
            float2 Zn = A[SW(1)];     // Z[2048]  (bitrev12(2048) = 1)
            float B0 = (Z0.x + Z0.y) * INVM;
            float BN = (Z0.x - Z0.y) * INVM;
            kw4[0] = make_float4(B0, BN, 0.0f, 0.0f);
            kw4[1] = make_float4(2.0f * INVM * Zn.x, 2.0f * INVM * Zn.y, 0.0f, 0.0f);
        } else {
            const int kc = NH - k;
            float2 Zk = A[SW(bitrev12(k))];
            float2 Zc = A[SW(bitrev12(kc))];
            float s_, c_;
            sincos_rev(-(float)k * (1.0f / 8192.0f), s_, c_);
            float2 P = make_float2(0.5f * (1.0f + s_), -0.5f * c_);
            float2 Q = make_float2(0.5f * (1.0f - s_),  0.5f * c_);
            float2 Bfk = cadd(cmul(P, Zk), cmul(Q, conjf(Zc)));
            float2 Bfc = cadd(cmul(conjf(P), Zc), cmul(conjf(Q), conjf(Zk)));
            Bfk.x *= INVM; Bfk.y *= INVM; Bfc.x *= INVM; Bfc.y *= INVM;
            float2 cBfc = conjf(Bfc), cBfk = conjf(Bfk);
            const float ap = 1.0f + s_, am = 1.0f - s_;
            float2 G1k = make_float2(ap * Bfk.x + am * cBfc.x, ap * Bfk.y + am * cBfc.y);
            float2 d1  = csub(Bfk, cBfc);
            float2 G2k = make_float2(-c_ * d1.y, c_ * d1.x);
            float2 G1c = make_float2(ap * Bfc.x + am * cBfk.x, ap * Bfc.y + am * cBfk.y);
            float2 d2  = csub(Bfc, cBfk);
            float2 G2c = make_float2(c_ * d2.y, -c_ * d2.x);
            kw4[2 * k]     = make_float4(G1k.x, G1k.y, G2k.x, G2k.y);
            kw4[2 * k + 1] = make_float4(G1c.x, G1c.y, G2c.x, G2c.y);
        }
    }
}

__global__ __launch_bounds__(NTHR)
void conv_kernel(const float* __restrict__ x, const float4* __restrict__ kw,
                 const float* __restrict__ Din, float* __restrict__ out)
{
    __shared__ float2 A[NH];   // 32 KiB -> 4-5 blocks/CU
    const int t = threadIdx.x;
    const int h = blockIdx.x >> 2;      // 4 adjacent blocks share kw[h] (L2)
    const int b = blockIdx.x & 3;
    const float Dh = Din[h];
    const float2* xrow2 = reinterpret_cast<const float2*>(x + ((size_t)b * Hdim + h) * Ldim);
    float2* orow2 = reinterpret_cast<float2*>(out + ((size_t)b * Hdim + h) * Ldim);
    const float4* kw4 = kw + (size_t)h * NH;

    load_fwd512(A, t, xrow2);
    __syncthreads();
    pass_fwd2<64, 6>(A, t);  __syncthreads();
    pass_fwd2<8, 3>(A, t);   __syncthreads();
    pass_fwd_unit(A, t);     __syncthreads();

    #pragma unroll 1
    for (int q = 0; q < 8; ++q) {
        const int k = t + NTHR * q;            // 0..2047
        if (k == 0) {
            float4 s0 = kw4[0];
            float4 s1 = kw4[1];
            float2 Z0 = A[SW(0)];
            float2 Zn = A[SW(1)];
            float a0 = Z0.x + Z0.y, aN = Z0.x - Z0.y;
            float y0 = a0 * s0.x, yN = aN * s0.y;
            A[SW(0)] = make_float2(y0 + yN, y0 - yN);
            A[SW(1)] = cmul(make_float2(s1.x, s1.y), Zn);
        } else {
            float4 gk = kw4[2 * k];
            float4 gc = kw4[2 * k + 1];
            const int j1 = SW(bitrev12(k));
            const int j2 = SW(bitrev12(NH - k));
            float2 Zk = A[j1], Zc = A[j2];
            A[j1] = cadd(cmul(make_float2(gk.x, gk.y), Zk),
                         cmul(make_float2(gk.z, gk.w), conjf(Zc)));
            A[j2] = cadd(cmul(make_float2(gc.x, gc.y), Zc),
                         cmul(make_float2(gc.z, gc.w), conjf(Zk)));
        }
    }
    __syncthreads();

    pass_inv_unit(A, t);     __syncthreads();
    pass_inv2<8, 3>(A, t);   __syncthreads();
    pass_inv2<64, 6>(A, t);  __syncthreads();
    {
        float2 v0;
        sincos_rev((float)t * (1.0f / 4096.0f), v0.y, v0.x);
        const float2 stp = make_float2(0.92387953251f, 0.38268343236f); // exp(+i pi/8)
        #pragma unroll 1
        for (int q = 0; q < 2; ++q) {
            const int g = t + NTHR * q;
            const float2 v = q ? cmul(v0, stp) : v0;
            float2 e[8];
            #pragma unroll
            for (int j = 0; j < 8; ++j) e[j] = A[SW(g + 512 * j)];
            inv8_low(e, v);
            #pragma unroll
            for (int j = 0; j < 4; ++j) {
                const int n = g + 512 * j;
                float2 xv = xrow2[n];
                orow2[n] = make_float2(e[j].x + Dh * xv.x, e[j].y + Dh * xv.y);
            }
        }
    }
}

extern "C" void kernel_launch(void* const* d_in, const int* in_sizes, int n_in,
                              void* d_out, int out_size, void* d_ws, size_t ws_size,
                              hipStream_t stream)
{
    const float* x  = (const float*)d_in[0];
    const float* k  = (const float*)d_in[1];
    const float* D  = (const float*)d_in[2];
    float* out = (float*)d_out;
    float4* kw = (float4*)d_ws;   // 1024 * 4096 * 16 B = 64 MB (ws verified in r9)

    hipLaunchKernelGGL(kspec_kernel, dim3(Hdim), dim3(NTHR), 0, stream, k, kw);
    hipLaunchKernelGGL(conv_kernel, dim3(Bdim * Hdim), dim3(NTHR), 0, stream,
                       x, kw, D, out);
}

// Round 12
// 110.058 us; speedup vs baseline: 4.5579x; 1.0234x over previous
//
#include <hip/hip_runtime.h>

// y[b,h,l] = sum_{m<=l} x[b,h,m] k[h,l-m] + D[h] x[b,h,l]   (C = 1)
//
// Half-size real-FFT, 16^3 factorization (r11 -> r12: 9 LDS phases -> 5).
// Per row: z[n] = x[2n] + i x[2n+1] (n<2048, 0 above); FFT_4096 as 3 radix-16
// register passes (strides 256, 16, 1); bin k at position bitrev12(k).
// Midpoint: V[p] = G1[p] Z[p] + G2[p] conj(Z[partner(p)]), G per-position
// from kspec (d_ws, 64 MB). Position p = 16a+j: k = 256*bitrev4(j)+bitrev8(a);
// partner octet a' = bitrev8(256-bitrev8(a)), element 15-j (a=0: self, fixed
// involution table). k=0 folds into G (G1=B0+BN, G2=i(B0-BN)) -> no special
// cases in conv. Stride-1 fwd + pairing + stride-1 inv fused in registers.
// Pad layout i+(i>>4) (34 KiB LDS): all LDS addrs = base + const*j.
//
// Resource law (r1-r11): 256-thr blocks + transient-only state -> natural
// VGPR alloc, zero spill. Check: WRITE_SIZE == output exactly.
#define Bdim 4
#define Hdim 1024
#define Ldim 4096
#define NH   4096
#define NTHR 256
#define R2C  0.70710678118654752440f
#define C16C 0.92387953251128675613f
#define S16C 0.38268343236508977173f
#define INVM (1.0f / 8192.0f)

__device__ __forceinline__ int PD(int i) { return i + (i >> 4); }
__device__ __forceinline__ int bitrev12(int k) { return (int)(__brev((unsigned)k) >> 20); }
__device__ __forceinline__ int bitrev8(int k)  { return (int)(__brev((unsigned)k) >> 24); }

__device__ __forceinline__ void sincos_rev(float f, float& s, float& c) {
#if __has_builtin(__builtin_amdgcn_sinf) && __has_builtin(__builtin_amdgcn_cosf)
    s = __builtin_amdgcn_sinf(f);
    c = __builtin_amdgcn_cosf(f);
#else
    __sincosf(f * 6.28318530717958647692f, &s, &c);
#endif
}

__device__ __forceinline__ float2 cadd(float2 a, float2 b) { return make_float2(a.x + b.x, a.y + b.y); }
__device__ __forceinline__ float2 csub(float2 a, float2 b) { return make_float2(a.x - b.x, a.y - b.y); }
__device__ __forceinline__ float2 cmul(float2 a, float2 b) {
    return make_float2(a.x * b.x - a.y * b.y, a.x * b.y + a.y * b.x);
}
__device__ __forceinline__ float2 mulc(float2 a, float cr, float ci) {
    return make_float2(a.x * cr - a.y * ci, a.x * ci + a.y * cr);
}
__device__ __forceinline__ float2 cmuli(float2 a)    { return make_float2(-a.y, a.x); }
__device__ __forceinline__ float2 cmulnegi(float2 a) { return make_float2(a.y, -a.x); }
__device__ __forceinline__ float2 conjf(float2 a)    { return make_float2(a.x, -a.y); }

// Butterfly macros. FBF: DIF (sum; diff*tw). IBF: DIT (u+e*tw; u-e*tw).
#define FBF(i, jj, tw)      { float2 u_ = e[i]; float2 d_ = csub(u_, e[jj]); e[i] = cadd(u_, e[jj]); e[jj] = cmul(d_, tw); }
#define FBFC(i, jj, cr, ci) { float2 u_ = e[i]; float2 d_ = csub(u_, e[jj]); e[i] = cadd(u_, e[jj]); e[jj] = mulc(d_, cr, ci); }
#define FBFN(i, jj)         { float2 u_ = e[i]; float2 d_ = csub(u_, e[jj]); e[i] = cadd(u_, e[jj]); e[jj] = cmulnegi(d_); }
#define BFU(i, jj)          { float2 u_ = e[i]; float2 v_ = e[jj]; e[i] = cadd(u_, v_); e[jj] = csub(u_, v_); }
#define IBF(i, jj, tw)      { float2 tv_ = cmul(e[jj], tw); float2 u_ = e[i]; e[i] = cadd(u_, tv_); e[jj] = csub(u_, tv_); }
#define IBFC(i, jj, cr, ci) { float2 tv_ = mulc(e[jj], cr, ci); float2 u_ = e[i]; e[i] = cadd(u_, tv_); e[jj] = csub(u_, tv_); }
#define IBFI(i, jj)         { float2 tv_ = cmuli(e[jj]); float2 u_ = e[i]; e[i] = cadd(u_, tv_); e[jj] = csub(u_, tv_); }

// ---- forward radix-16 (4 fused radix-2 DIF stages), w = exp(-2pi i b/(16S)) ----
__device__ __forceinline__ void fwd16_tail(float2 e[16], float2 w) {
    float2 w2 = cmul(w, w);
    float2 u1 = mulc(w2, R2C, -R2C);
    float2 u2 = cmulnegi(w2);
    float2 u3 = cmulnegi(u1);
    FBF(0,4,w2) FBF(1,5,u1) FBF(2,6,u2) FBF(3,7,u3)
    FBF(8,12,w2) FBF(9,13,u1) FBF(10,14,u2) FBF(11,15,u3)
    float2 w4 = cmul(w2, w2);
    float2 w4n = cmulnegi(w4);
    FBF(0,2,w4) FBF(1,3,w4n) FBF(4,6,w4) FBF(5,7,w4n)
    FBF(8,10,w4) FBF(9,11,w4n) FBF(12,14,w4) FBF(13,15,w4n)
    float2 w8 = cmul(w4, w4);
    FBF(0,1,w8) FBF(2,3,w8) FBF(4,5,w8) FBF(6,7,w8)
    FBF(8,9,w8) FBF(10,11,w8) FBF(12,13,w8) FBF(14,15,w8)
}
__device__ __forceinline__ void fwd16(float2 e[16], float2 w) {
    float2 t1 = mulc(w, C16C, -S16C);
    float2 t2 = mulc(w, R2C, -R2C);
    float2 t3 = mulc(w, S16C, -C16C);
    float2 t4 = cmulnegi(w);
    float2 t5 = cmulnegi(t1);
    float2 t6 = cmulnegi(t2);
    float2 t7 = cmulnegi(t3);
    FBF(0,8,w) FBF(1,9,t1) FBF(2,10,t2) FBF(3,11,t3)
    FBF(4,12,t4) FBF(5,13,t5) FBF(6,14,t6) FBF(7,15,t7)
    fwd16_tail(e, w);
}
// First pass variant: e[8..15] are implicit zeros (zero-padded upper half).
__device__ __forceinline__ void fwd16_zero(float2 e[16], float2 w) {
    float2 t1 = mulc(w, C16C, -S16C);
    float2 t2 = mulc(w, R2C, -R2C);
    float2 t3 = mulc(w, S16C, -C16C);
    e[8]  = cmul(e[0], w);
    e[9]  = cmul(e[1], t1);
    e[10] = cmul(e[2], t2);
    e[11] = cmul(e[3], t3);
    e[12] = cmul(e[4], cmulnegi(w));
    e[13] = cmul(e[5], cmulnegi(t1));
    e[14] = cmul(e[6], cmulnegi(t2));
    e[15] = cmul(e[7], cmulnegi(t3));
    fwd16_tail(e, w);
}
// w = 1 (stride-1 pass): constant twiddles only.
__device__ __forceinline__ void fwd16_unit(float2 e[16]) {
    BFU(0,8)
    FBFC(1,9,   C16C, -S16C)
    FBFC(2,10,  R2C,  -R2C)
    FBFC(3,11,  S16C, -C16C)
    FBFN(4,12)
    FBFC(5,13, -S16C, -C16C)
    FBFC(6,14, -R2C,  -R2C)
    FBFC(7,15, -C16C, -S16C)
    BFU(0,4)  FBFC(1,5,  R2C, -R2C) FBFN(2,6)   FBFC(3,7,  -R2C, -R2C)
    BFU(8,12) FBFC(9,13, R2C, -R2C) FBFN(10,14) FBFC(11,15,-R2C, -R2C)
    BFU(0,2)  FBFN(1,3)  BFU(4,6)   FBFN(5,7)
    BFU(8,10) FBFN(9,11) BFU(12,14) FBFN(13,15)
    BFU(0,1) BFU(2,3) BFU(4,5) BFU(6,7) BFU(8,9) BFU(10,11) BFU(12,13) BFU(14,15)
}

// ---- inverse radix-16 (4 fused radix-2 DIT stages), v = exp(+2pi i b/(16S)) ----
__device__ __forceinline__ void inv16_head(float2 e[16], float2 v) {
    float2 v2 = cmul(v, v);
    float2 v4 = cmul(v2, v2);
    float2 v8 = cmul(v4, v4);
    IBF(0,1,v8) IBF(2,3,v8) IBF(4,5,v8) IBF(6,7,v8)
    IBF(8,9,v8) IBF(10,11,v8) IBF(12,13,v8) IBF(14,15,v8)
    float2 v4i = cmuli(v4);
    IBF(0,2,v4) IBF(1,3,v4i) IBF(4,6,v4) IBF(5,7,v4i)
    IBF(8,10,v4) IBF(9,11,v4i) IBF(12,14,v4) IBF(13,15,v4i)
    float2 p1 = mulc(v2, R2C, R2C);
    float2 p2 = cmuli(v2);
    float2 p3 = cmuli(p1);
    IBF(0,4,v2) IBF(1,5,p1) IBF(2,6,p2) IBF(3,7,p3)
    IBF(8,12,v2) IBF(9,13,p1) IBF(10,14,p2) IBF(11,15,p3)
}
__device__ __forceinline__ void inv16(float2 e[16], float2 v) {
    inv16_head(e, v);
    float2 s1 = mulc(v, C16C, S16C);
    float2 s2 = mulc(v, R2C, R2C);
    float2 s3 = mulc(v, S16C, C16C);
    IBF(0,8,v) IBF(1,9,s1) IBF(2,10,s2) IBF(3,11,s3)
    float2 s4 = cmuli(v);
    float2 s5 = cmuli(s1);
    float2 s6 = cmuli(s2);
    float2 s7 = cmuli(s3);
    IBF(4,12,s4) IBF(5,13,s5) IBF(6,14,s6) IBF(7,15,s7)
}
// Last stage '+' outputs only (low half n<2048 of the final S=256 pass).
__device__ __forceinline__ void inv16_low(float2 e[16], float2 v) {
    inv16_head(e, v);
    float2 s1 = mulc(v, C16C, S16C);
    float2 s2 = mulc(v, R2C, R2C);
    float2 s3 = mulc(v, S16C, C16C);
    e[0] = cadd(e[0], cmul(e[8],  v));
    e[1] = cadd(e[1], cmul(e[9],  s1));
    e[2] = cadd(e[2], cmul(e[10], s2));
    e[3] = cadd(e[3], cmul(e[11], s3));
    e[4] = cadd(e[4], cmul(e[12], cmuli(v)));
    e[5] = cadd(e[5], cmul(e[13], cmuli(s1)));
    e[6] = cadd(e[6], cmul(e[14], cmuli(s2)));
    e[7] = cadd(e[7], cmul(e[15], cmuli(s3)));
}
__device__ __forceinline__ void inv16_unit(float2 e[16]) {
    BFU(0,1) BFU(2,3) BFU(4,5) BFU(6,7) BFU(8,9) BFU(10,11) BFU(12,13) BFU(14,15)
    BFU(0,2)  IBFI(1,3)  BFU(4,6)   IBFI(5,7)
    BFU(8,10) IBFI(9,11) BFU(12,14) IBFI(13,15)
    BFU(0,4)  IBFC(1,5,  R2C, R2C) IBFI(2,6)   IBFC(3,7,  -R2C, R2C)
    BFU(8,12) IBFC(9,13, R2C, R2C) IBFI(10,14) IBFC(11,15,-R2C, R2C)
    BFU(0,8)
    IBFC(1,9,   C16C, S16C)
    IBFC(2,10,  R2C,  R2C)
    IBFC(3,11,  S16C, C16C)
    IBFI(4,12)
    IBFC(5,13, -S16C, C16C)
    IBFC(6,14, -R2C,  R2C)
    IBFC(7,15, -C16C, S16C)
}

// a=0 self-pair involution: partner element of j (verified bin-by-bin).
__device__ __forceinline__ constexpr int jp0_of(int j) {
    constexpr int tbl[16] = {0,1,3,2,7,6,5,4,15,14,13,12,11,10,9,8};
    return tbl[j];
}

// ======================= kernel 1: per-position G -> d_ws =======================
__global__ __launch_bounds__(NTHR)
void kspec_kernel(const float* __restrict__ kin, float4* __restrict__ kw)
{
    __shared__ float2 A[NH + (NH >> 4)];   // 34 KiB padded
    const int t = threadIdx.x;
    const int h = blockIdx.x;
    const float2* krow2 = (const float2*)(kin + (size_t)h * Ldim);

    {   // P1: load packed + fwd16 (S=256)
        float2 w; sincos_rev(-(float)t * (1.0f / 4096.0f), w.y, w.x);
        float2 e[16];
        #pragma unroll
        for (int j = 0; j < 8; ++j) e[j] = krow2[t + 256 * j];
        fwd16_zero(e, w);
        const int pg = t + (t >> 4);
        #pragma unroll
        for (int j = 0; j < 16; ++j) A[pg + 272 * j] = e[j];
    }
    __syncthreads();
    {   // P2: fwd16 (S=16)
        float2 w; sincos_rev(-(float)(t & 15) * (1.0f / 256.0f), w.y, w.x);
        const int base = ((t >> 4) << 8) | (t & 15);
        const int pb = base + (base >> 4);
        float2 e[16];
        #pragma unroll
        for (int j = 0; j < 16; ++j) e[j] = A[pb + 17 * j];
        fwd16(e, w);
        #pragma unroll
        for (int j = 0; j < 16; ++j) A[pb + 17 * j] = e[j];
    }
    __syncthreads();
    {   // P3: fwd16_unit (S=1) per hexadectet
        const int baseA = 17 * t;
        float2 e[16];
        #pragma unroll
        for (int j = 0; j < 16; ++j) e[j] = A[baseA + j];
        fwd16_unit(e);
        #pragma unroll
        for (int j = 0; j < 16; ++j) A[baseA + j] = e[j];
    }
    __syncthreads();
    // G phase: per position p, bin k = bitrev12(p).
    float4* kwp = kw + (size_t)h * NH;
    #pragma unroll 1
    for (int q = 0; q < 16; ++q) {
        const int p = t + 256 * q;
        const int k = bitrev12(p);
        if (k == 0) {
            float2 Z0 = A[0];
            float B0 = (Z0.x + Z0.y) * INVM;   // rfft(k)[0]    (real)
            float BN = (Z0.x - Z0.y) * INVM;   // rfft(k)[4096] (real)
            kwp[0] = make_float4(B0 + BN, 0.0f, 0.0f, B0 - BN);  // G1, G2=i(B0-BN)
        } else {
            const int kc = 4096 - k;
            float2 Zk = A[PD(p)];
            float2 Zc = A[PD(bitrev12(kc))];
            float s_, c_;
            sincos_rev(-(float)k * (1.0f / 8192.0f), s_, c_);
            float2 P = make_float2(0.5f * (1.0f + s_), -0.5f * c_);
            float2 Q = make_float2(0.5f * (1.0f - s_),  0.5f * c_);
            float2 Bfk = cadd(cmul(P, Zk), cmul(Q, conjf(Zc)));
            float2 Bfc = cadd(cmul(conjf(P), Zc), cmul(conjf(Q), conjf(Zk)));
            Bfk.x *= INVM; Bfk.y *= INVM; Bfc.x *= INVM; Bfc.y *= INVM;
            float2 cBfc = conjf(Bfc);
            const float ap_ = 1.0f + s_, am_ = 1.0f - s_;
            float2 G1 = make_float2(ap_ * Bfk.x + am_ * cBfc.x,
                                    ap_ * Bfk.y + am_ * cBfc.y);
            float2 d1 = csub(Bfk, cBfc);
            float2 G2 = make_float2(-c_ * d1.y, c_ * d1.x);   // i c d1
            kwp[p] = make_float4(G1.x, G1.y, G2.x, G2.y);
        }
    }
}

// ================= kernel 2: per (h, b) row conv =================
__global__ __launch_bounds__(NTHR)
void conv_kernel(const float* __restrict__ x, const float4* __restrict__ kw,
                 const float* __restrict__ Din, float* __restrict__ out)
{
    __shared__ float2 A[NH + (NH >> 4)];   // 34 KiB -> 4 blocks/CU
    const int t = threadIdx.x;
    const int h = blockIdx.x >> 2;         // 4 adjacent blocks share kw[h]
    const int b = blockIdx.x & 3;
    const float Dh = Din[h];
    const float2* xrow2 = (const float2*)(x + ((size_t)b * Hdim + h) * Ldim);
    float2* orow2 = (float2*)(out + ((size_t)b * Hdim + h) * Ldim);

    float2 xr[8];                          // kept for the D*x skip (same n-set)
    {   // P1: load packed x + fwd16 (S=256)
        float2 w; sincos_rev(-(float)t * (1.0f / 4096.0f), w.y, w.x);
        float2 e[16];
        #pragma unroll
        for (int j = 0; j < 8; ++j) { xr[j] = xrow2[t + 256 * j]; e[j] = xr[j]; }
        fwd16_zero(e, w);
        const int pg = t + (t >> 4);
        #pragma unroll
        for (int j = 0; j < 16; ++j) A[pg + 272 * j] = e[j];
    }
    __syncthreads();
    {   // P2: fwd16 (S=16)
        float2 w; sincos_rev(-(float)(t & 15) * (1.0f / 256.0f), w.y, w.x);
        const int base = ((t >> 4) << 8) | (t & 15);
        const int pb = base + (base >> 4);
        float2 e[16];
        #pragma unroll
        for (int j = 0; j < 16; ++j) e[j] = A[pb + 17 * j];
        fwd16(e, w);
        #pragma unroll
        for (int j = 0; j < 16; ++j) A[pb + 17 * j] = e[j];
    }
    __syncthreads();
    {   // P3 fused: fwd16_unit + pairing (V = G1 Z + G2 conj(Zpart)) + inv16_unit
        const int a = t;
        const int s = bitrev8(a);
        const int ap = bitrev8((256 - s) & 255);   // partner hexadectet (a==0 -> 0)
        const int baseA = 17 * a;
        const int baseB = 17 * ap;
        float2 za[16], zb[16];
        #pragma unroll
        for (int j = 0; j < 16; ++j) za[j] = A[baseA + j];
        #pragma unroll
        for (int j = 0; j < 16; ++j) zb[j] = A[baseB + j];
        fwd16_unit(za);
        fwd16_unit(zb);                    // self case: duplicate compute, correct
        const float4* Gp = kw + (size_t)h * NH + (a << 4);
        const bool a0 = (a == 0);
        #pragma unroll
        for (int j = 0; j < 16; ++j) {
            float4 g = Gp[j];
            float2 zpart = a0 ? zb[jp0_of(j)] : zb[15 - j];  // both compile-time idx
            za[j] = cadd(cmul(make_float2(g.x, g.y), za[j]),
                         cmul(make_float2(g.z, g.w), conjf(zpart)));
        }
        inv16_unit(za);
        #pragma unroll
        for (int j = 0; j < 16; ++j) A[baseA + j] = za[j];
    }
    __syncthreads();
    {   // P4: inv16 (S=16)
        float2 v; sincos_rev((float)(t & 15) * (1.0f / 256.0f), v.y, v.x);
        const int base = ((t >> 4) << 8) | (t & 15);
        const int pb = base + (base >> 4);
        float2 e[16];
        #pragma unroll
        for (int j = 0; j < 16; ++j) e[j] = A[pb + 17 * j];
        inv16(e, v);
        #pragma unroll
        for (int j = 0; j < 16; ++j) A[pb + 17 * j] = e[j];
    }
    __syncthreads();
    {   // P5: inv16 low half (S=256) + epilogue with D*x skip from regs
        float2 v; sincos_rev((float)t * (1.0f / 4096.0f), v.y, v.x);
        const int pg = t + (t >> 4);
        float2 e[16];
        #pragma unroll
        for (int j = 0; j < 16; ++j) e[j] = A[pg + 272 * j];
        inv16_low(e, v);
        #pragma unroll
        for (int j = 0; j < 8; ++j) {
            orow2[t + 256 * j] = make_float2(e[j].x + Dh * xr[j].x,
                                             e[j].y + Dh * xr[j].y);
        }
    }
}

extern "C" void kernel_launch(void* const* d_in, const int* in_sizes, int n_in,
                              void* d_out, int out_size, void* d_ws, size_t ws_size,
                              hipStream_t stream)
{
    const float* x  = (const float*)d_in[0];
    const float* k  = (const float*)d_in[1];
    const float* D  = (const float*)d_in[2];
    float* out = (float*)d_out;
    float4* kw = (float4*)d_ws;   // 1024 * 4096 * 16 B = 64 MB

    hipLaunchKernelGGL(kspec_kernel, dim3(Hdim), dim3(NTHR), 0, stream, k, kw);
    hipLaunchKernelGGL(conv_kernel, dim3(Bdim * Hdim), dim3(NTHR), 0, stream,
                       x, kw, D, out);
}